// Round 4
// baseline (42.818 us; speedup 1.0000x reference)
//
#include <hip/hip_runtime.h>
#include <math.h>
#include <float.h>

#define B_ 2
#define NQ 1024
#define NO 1024
#define LAT 128
#define NHEADS 4
#define RADIUS_ 0.5f
#define LN_EPS_ 1e-5f
#define TILE 512
#define TILE_P (TILE + 8)

#define V_BYTES ((size_t)B_ * NO * LAT * 4)

typedef float v2f __attribute__((ext_vector_type(2)));
__device__ __forceinline__ v2f splat2(float x) { return (v2f){x, x}; }

__device__ __forceinline__ float selh(int h, float a, float b, float c, float d) {
  return h == 0 ? a : (h == 1 ? b : (h == 2 ? c : d));
}

// workspace: v (B*NO*LAT f32) | A4 (LAT float4) | CW8 (2*LAT float4)
// CW8[2j]   = (W1[3]-W1[6], W1[4]-W1[7], W1[5]-W1[8], W1[9]) col j
// CW8[2j+1] = (W2[j][0..3])
// A4[j]     = (W1[0]+W1[6], W1[1]+W1[7], W1[2]+W1[8], b1[j])

// ---------------- prep: v = LayerNorm(h_obs) @ Wv + bv, 4 rows/block -------
__global__ __launch_bounds__(256) void gano_prep_kernel(
    const float* __restrict__ h_obs, const float* __restrict__ ln_g,
    const float* __restrict__ ln_b, const float* __restrict__ Wv,
    const float* __restrict__ bv, const float* __restrict__ W1,
    const float* __restrict__ b1, const float* __restrict__ W2,
    float* __restrict__ v_out,
    float4* __restrict__ A4, float4* __restrict__ CW8, int write_derived)
{
  const int tid = threadIdx.x;
  const int j = tid & 127;
  const int half = tid >> 7;
  const int wave = tid >> 6;
  const int lane = tid & 63;
  const int r0 = blockIdx.x * 4 + half * 2;

  __shared__ float s_redA[2][4];
  __shared__ float s_redB[2][4];
  __shared__ __align__(16) float s_hn[4][LAT];

  const float x0 = h_obs[(size_t)r0 * LAT + j];
  const float x1 = h_obs[(size_t)(r0 + 1) * LAT + j];
  float s0 = x0, s1 = x1;
  #pragma unroll
  for (int off = 32; off >= 1; off >>= 1) {
    s0 += __shfl_down(s0, off);
    s1 += __shfl_down(s1, off);
  }
  if (lane == 0) { s_redA[0][wave] = s0; s_redA[1][wave] = s1; }
  __syncthreads();
  const float mu0 = (s_redA[0][half * 2] + s_redA[0][half * 2 + 1]) * (1.0f / LAT);
  const float mu1 = (s_redA[1][half * 2] + s_redA[1][half * 2 + 1]) * (1.0f / LAT);
  const float d0 = x0 - mu0, d1 = x1 - mu1;
  float q0 = d0 * d0, q1 = d1 * d1;
  #pragma unroll
  for (int off = 32; off >= 1; off >>= 1) {
    q0 += __shfl_down(q0, off);
    q1 += __shfl_down(q1, off);
  }
  if (lane == 0) { s_redB[0][wave] = q0; s_redB[1][wave] = q1; }
  __syncthreads();
  const float var0 = (s_redB[0][half * 2] + s_redB[0][half * 2 + 1]) * (1.0f / LAT);
  const float var1 = (s_redB[1][half * 2] + s_redB[1][half * 2 + 1]) * (1.0f / LAT);
  const float g = ln_g[j], be = ln_b[j];
  s_hn[half * 2 + 0][j] = d0 * rsqrtf(var0 + LN_EPS_) * g + be;
  s_hn[half * 2 + 1][j] = d1 * rsqrtf(var1 + LN_EPS_) * g + be;
  __syncthreads();

  float a0 = 0.0f, a1 = 0.0f;
  const float4* h0 = (const float4*)s_hn[half * 2 + 0];
  const float4* h1 = (const float4*)s_hn[half * 2 + 1];
  #pragma unroll 4
  for (int k4 = 0; k4 < LAT / 4; ++k4) {
    const float4 u0 = h0[k4];
    const float4 u1 = h1[k4];
    const float w0 = Wv[(k4 * 4 + 0) * LAT + j];
    const float w1 = Wv[(k4 * 4 + 1) * LAT + j];
    const float w2 = Wv[(k4 * 4 + 2) * LAT + j];
    const float w3 = Wv[(k4 * 4 + 3) * LAT + j];
    a0 = fmaf(u0.x, w0, a0); a0 = fmaf(u0.y, w1, a0);
    a0 = fmaf(u0.z, w2, a0); a0 = fmaf(u0.w, w3, a0);
    a1 = fmaf(u1.x, w0, a1); a1 = fmaf(u1.y, w1, a1);
    a1 = fmaf(u1.z, w2, a1); a1 = fmaf(u1.w, w3, a1);
  }
  const float bvj = bv[j];
  v_out[(size_t)(r0 + 0) * LAT + j] = a0 + bvj;
  v_out[(size_t)(r0 + 1) * LAT + j] = a1 + bvj;

  if (write_derived && blockIdx.x == 0 && tid < LAT) {
    float w[10];
    #pragma unroll
    for (int k = 0; k < 10; ++k) w[k] = W1[k * LAT + tid];
    A4[tid] = make_float4(w[0] + w[6], w[1] + w[7], w[2] + w[8], b1[tid]);
    CW8[2 * tid + 0] = make_float4(w[3] - w[6], w[4] - w[7], w[5] - w[8], w[9]);
    CW8[2 * tid + 1] = make_float4(W2[tid * NHEADS + 0], W2[tid * NHEADS + 1],
                                   W2[tid * NHEADS + 2], W2[tid * NHEADS + 3]);
  }
}

// ---------------- main: one block = one (b,q), 256 threads -----------------
template <bool DERIVED>
__global__ __launch_bounds__(256, 6) void gano_main_kernel(
    const float* __restrict__ pos_obs, const float* __restrict__ pos_query,
    const int* __restrict__ obs_mask,
    const float* __restrict__ W1, const float* __restrict__ b1,
    const float4* __restrict__ W2v, const float* __restrict__ b2,
    const float* __restrict__ v,
    const float4* __restrict__ A4, const float4* __restrict__ CW8,
    float* __restrict__ out)
{
  __shared__ __align__(16) float s_Q[LAT];
  __shared__ int   s_vidx[NO];
  __shared__ float s_vdist[NO];
  __shared__ float s_p[NHEADS][TILE_P];
  __shared__ int   s_cnt[16];
  __shared__ float s_red[NHEADS][4];
  __shared__ float s_zred[NHEADS][4];
  __shared__ __align__(16) float s_part[4][LAT];

  const int tid = threadIdx.x;
  const int wave = tid >> 6, lane = tid & 63;
  const int bid = blockIdx.x;
  const int b = bid >> 10, q = bid & (NQ - 1);

  const float qx = pos_query[((size_t)b * NQ + q) * 3 + 0];
  const float qy = pos_query[((size_t)b * NQ + q) * 3 + 1];
  const float qz = pos_query[((size_t)b * NQ + q) * 3 + 2];

  if (tid < LAT) {
    float a0, a1, a2, a3;
    if constexpr (DERIVED) {
      const float4 a = A4[tid];
      a0 = a.x; a1 = a.y; a2 = a.z; a3 = a.w;
    } else {
      a0 = W1[0 * LAT + tid] + W1[6 * LAT + tid];
      a1 = W1[1 * LAT + tid] + W1[7 * LAT + tid];
      a2 = W1[2 * LAT + tid] + W1[8 * LAT + tid];
      a3 = b1[tid];
    }
    s_Q[tid] = fmaf(qx, a0, fmaf(qy, a1, fmaf(qz, a2, a3)));
  }

  // ---- compaction ----
  const float* pob = pos_obs + (size_t)b * NO * 3;
  const int*   om  = obs_mask + (size_t)b * NO;
  float dists[4];
  unsigned long long bals[4];
  #pragma unroll
  for (int rd = 0; rd < 4; ++rd) {
    const int o = (rd << 8) + tid;
    const float ox = pob[o * 3 + 0], oy = pob[o * 3 + 1], oz = pob[o * 3 + 2];
    const float rx = qx - ox, ry = qy - oy, rz = qz - oz;
    const float dist = sqrtf(rx * rx + ry * ry + rz * rz);
    const int ok = (om[o] != 0) && (dist <= RADIUS_);
    const unsigned long long bal = __ballot(ok);
    if (lane == 0) s_cnt[(rd << 2) + wave] = __popcll(bal);
    bals[rd] = bal;
    dists[rd] = dist;
  }
  __syncthreads();
  int Nv = 0;
  #pragma unroll
  for (int k = 0; k < 16; ++k) Nv += s_cnt[k];
  #pragma unroll
  for (int rd = 0; rd < 4; ++rd) {
    const int slot = (rd << 2) + wave;
    int base = 0;
    for (int k = 0; k < slot; ++k) base += s_cnt[k];
    if ((bals[rd] >> lane) & 1ull) {
      const int pos = base + __popcll(bals[rd] & ((1ull << lane) - 1ull));
      s_vidx[pos] = (rd << 8) + tid;
      s_vdist[pos] = dists[rd];
    }
  }
  __syncthreads();

  // ---- per-thread mappings ----
  const int c5 = tid & 31;       // PV column group: cols 4*c5 .. 4*c5+3
  const int phase = tid >> 5;    // PV item phase 0..7
  const int hh = c5 >> 3;        // head of PV column group
  // MLP slot pair, rotated across physical waves by bid for SIMD balance
  const int vslot = (((wave + bid) & 3) << 7) + (lane << 1);

  float ax = 0.f, ay = 0.f, az = 0.f, aw = 0.f;
  float m0 = -FLT_MAX, m1 = -FLT_MAX, m2 = -FLT_MAX, m3 = -FLT_MAX;
  float z0 = 0.f, z1 = 0.f, z2 = 0.f, z3 = 0.f;
  const float b20 = b2[0], b21 = b2[1], b22 = b2[2], b23 = b2[3];
  const float* vcol = v + (size_t)b * NO * LAT + (c5 << 2);

  const int ntiles = (Nv + TILE - 1) >> 9;
  for (int tile = 0; tile < ntiles; ++tile) {
    const int tbase = tile << 9;
    const int tA = tbase + vslot, tB = tA + 1;
    const bool aA = tA < Nv, aB = tB < Nv;
    v2f L0 = splat2(-FLT_MAX), L1 = L0, L2 = L0, L3 = L0;
    if (__any(aA)) {
      const int cA = aA ? tA : Nv - 1;
      const int cB = aB ? tB : Nv - 1;
      const int iA = s_vidx[cA], iB = s_vidx[cB];
      const v2f dd = {s_vdist[cA], s_vdist[cB]};
      const v2f ox2 = {pob[iA * 3 + 0], pob[iB * 3 + 0]};
      const v2f oy2 = {pob[iA * 3 + 1], pob[iB * 3 + 1]};
      const v2f oz2 = {pob[iA * 3 + 2], pob[iB * 3 + 2]};
      v2f A0 = splat2(b20), A1 = splat2(b21), A2 = splat2(b22), A3 = splat2(b23);
      #pragma unroll 2
      for (int j4 = 0; j4 < LAT / 4; ++j4) {
        const float4 q4 = *(const float4*)&s_Q[j4 << 2];
        #pragma unroll
        for (int u = 0; u < 4; ++u) {
          const int jj = (j4 << 2) + u;
          float4 cw, w2;
          if constexpr (DERIVED) {
            cw = CW8[2 * jj + 0];
            w2 = CW8[2 * jj + 1];
          } else {
            cw = make_float4(W1[3 * LAT + jj] - W1[6 * LAT + jj],
                             W1[4 * LAT + jj] - W1[7 * LAT + jj],
                             W1[5 * LAT + jj] - W1[8 * LAT + jj],
                             W1[9 * LAT + jj]);
            w2 = W2v[jj];
          }
          const float qj = (u == 0) ? q4.x : (u == 1) ? q4.y : (u == 2) ? q4.z : q4.w;
          v2f gg = __builtin_elementwise_fma(ox2, splat2(cw.x), splat2(qj));
          gg = __builtin_elementwise_fma(oy2, splat2(cw.y), gg);
          gg = __builtin_elementwise_fma(oz2, splat2(cw.z), gg);
          gg = __builtin_elementwise_fma(dd,  splat2(cw.w), gg);
          gg = __builtin_elementwise_max(gg, splat2(0.0f));
          A0 = __builtin_elementwise_fma(gg, splat2(w2.x), A0);
          A1 = __builtin_elementwise_fma(gg, splat2(w2.y), A1);
          A2 = __builtin_elementwise_fma(gg, splat2(w2.z), A2);
          A3 = __builtin_elementwise_fma(gg, splat2(w2.w), A3);
        }
      }
      if (aA) { L0.x = A0.x; L1.x = A1.x; L2.x = A2.x; L3.x = A3.x; }
      if (aB) { L0.y = A0.y; L1.y = A1.y; L2.y = A2.y; L3.y = A3.y; }
    }

    // tile max per head
    float t0 = fmaxf(L0.x, L0.y), t1 = fmaxf(L1.x, L1.y);
    float t2 = fmaxf(L2.x, L2.y), t3 = fmaxf(L3.x, L3.y);
    #pragma unroll
    for (int off = 32; off >= 1; off >>= 1) {
      t0 = fmaxf(t0, __shfl_down(t0, off));
      t1 = fmaxf(t1, __shfl_down(t1, off));
      t2 = fmaxf(t2, __shfl_down(t2, off));
      t3 = fmaxf(t3, __shfl_down(t3, off));
    }
    if (lane == 0) { s_red[0][wave] = t0; s_red[1][wave] = t1;
                     s_red[2][wave] = t2; s_red[3][wave] = t3; }
    __syncthreads();
    const float x0 = fmaxf(fmaxf(s_red[0][0], s_red[0][1]), fmaxf(s_red[0][2], s_red[0][3]));
    const float x1 = fmaxf(fmaxf(s_red[1][0], s_red[1][1]), fmaxf(s_red[1][2], s_red[1][3]));
    const float x2 = fmaxf(fmaxf(s_red[2][0], s_red[2][1]), fmaxf(s_red[2][2], s_red[2][3]));
    const float x3 = fmaxf(fmaxf(s_red[3][0], s_red[3][1]), fmaxf(s_red[3][2], s_red[3][3]));
    const float nm0 = fmaxf(m0, x0), nm1 = fmaxf(m1, x1);
    const float nm2 = fmaxf(m2, x2), nm3 = fmaxf(m3, x3);
    const float sc0 = __expf(m0 - nm0), sc1 = __expf(m1 - nm1);
    const float sc2 = __expf(m2 - nm2), sc3 = __expf(m3 - nm3);
    m0 = nm0; m1 = nm1; m2 = nm2; m3 = nm3;

    const v2f P0 = {__expf(L0.x - nm0), __expf(L0.y - nm0)};
    const v2f P1 = {__expf(L1.x - nm1), __expf(L1.y - nm1)};
    const v2f P2 = {__expf(L2.x - nm2), __expf(L2.y - nm2)};
    const v2f P3 = {__expf(L3.x - nm3), __expf(L3.y - nm3)};
    *(v2f*)&s_p[0][vslot] = P0;
    *(v2f*)&s_p[1][vslot] = P1;
    *(v2f*)&s_p[2][vslot] = P2;
    *(v2f*)&s_p[3][vslot] = P3;
    float u0 = P0.x + P0.y, u1 = P1.x + P1.y, u2 = P2.x + P2.y, u3 = P3.x + P3.y;
    #pragma unroll
    for (int off = 32; off >= 1; off >>= 1) {
      u0 += __shfl_down(u0, off);
      u1 += __shfl_down(u1, off);
      u2 += __shfl_down(u2, off);
      u3 += __shfl_down(u3, off);
    }
    if (lane == 0) { s_zred[0][wave] = u0; s_zred[1][wave] = u1;
                     s_zred[2][wave] = u2; s_zred[3][wave] = u3; }
    __syncthreads();   // also makes s_p visible
    z0 = z0 * sc0 + (s_zred[0][0] + s_zred[0][1] + s_zred[0][2] + s_zred[0][3]);
    z1 = z1 * sc1 + (s_zred[1][0] + s_zred[1][1] + s_zred[1][2] + s_zred[1][3]);
    z2 = z2 * sc2 + (s_zred[2][0] + s_zred[2][1] + s_zred[2][2] + s_zred[2][3]);
    z3 = z3 * sc3 + (s_zred[3][0] + s_zred[3][1] + s_zred[3][2] + s_zred[3][3]);
    const float scme = selh(hh, sc0, sc1, sc2, sc3);
    ax *= scme; ay *= scme; az *= scme; aw *= scme;

    // PV over this tile
    const int tcnt = min(TILE, Nv - tbase);
    int it = phase;
    float bx = 0.f, by = 0.f, bz = 0.f, bw = 0.f;
    for (; it + 8 < tcnt; it += 16) {
      const float pA = s_p[hh][it];
      const float pB = s_p[hh][it + 8];
      const int iA = s_vidx[tbase + it];
      const int iB = s_vidx[tbase + it + 8];
      const float4 vA = *(const float4*)(vcol + (size_t)iA * LAT);
      const float4 vB = *(const float4*)(vcol + (size_t)iB * LAT);
      ax = fmaf(pA, vA.x, ax); ay = fmaf(pA, vA.y, ay);
      az = fmaf(pA, vA.z, az); aw = fmaf(pA, vA.w, aw);
      bx = fmaf(pB, vB.x, bx); by = fmaf(pB, vB.y, by);
      bz = fmaf(pB, vB.z, bz); bw = fmaf(pB, vB.w, bw);
    }
    if (it < tcnt) {
      const float pA = s_p[hh][it];
      const int iA = s_vidx[tbase + it];
      const float4 vA = *(const float4*)(vcol + (size_t)iA * LAT);
      ax = fmaf(pA, vA.x, ax); ay = fmaf(pA, vA.y, ay);
      az = fmaf(pA, vA.z, az); aw = fmaf(pA, vA.w, aw);
    }
    ax += bx; ay += by; az += bz; aw += bw;
    if (tile + 1 < ntiles) __syncthreads();
  }

  // ---- final reduce ----
  ax += __shfl_down(ax, 32);
  ay += __shfl_down(ay, 32);
  az += __shfl_down(az, 32);
  aw += __shfl_down(aw, 32);
  if (lane < 32) {
    *(float4*)&s_part[wave][lane << 2] = make_float4(ax, ay, az, aw);
  }
  __syncthreads();
  if (tid < LAT) {
    const float r4 = s_part[0][tid] + s_part[1][tid] + s_part[2][tid] + s_part[3][tid];
    const int h = tid >> 5;
    const float zz = selh(h, z0, z1, z2, z3);
    const float r = (Nv > 0) ? (r4 / zz) : 0.0f;
    out[((size_t)b * NQ + q) * LAT + tid] = r;
  }
}

extern "C" void kernel_launch(void* const* d_in, const int* in_sizes, int n_in,
                              void* d_out, int out_size, void* d_ws, size_t ws_size,
                              hipStream_t stream) {
  const float* h_obs     = (const float*)d_in[0];
  const float* pos_obs   = (const float*)d_in[1];
  const float* pos_query = (const float*)d_in[2];
  const int*   obs_mask  = (const int*)d_in[3];
  const float* W1        = (const float*)d_in[4];
  const float* b1        = (const float*)d_in[5];
  const float* W2        = (const float*)d_in[6];
  const float* b2        = (const float*)d_in[7];
  const float* ln_g      = (const float*)d_in[8];
  const float* ln_b      = (const float*)d_in[9];
  const float* Wv        = (const float*)d_in[10];
  const float* bv        = (const float*)d_in[11];
  float* outp = (float*)d_out;
  float* v    = (float*)d_ws;

  const size_t need = V_BYTES + 3 * LAT * sizeof(float4);
  const int derived = (ws_size >= need) ? 1 : 0;
  float4* A4  = (float4*)((char*)d_ws + V_BYTES);
  float4* CW8 = A4 + LAT;
  if (!derived) { A4 = (float4*)d_ws; CW8 = (float4*)d_ws; }

  gano_prep_kernel<<<(B_ * NO) / 4, 256, 0, stream>>>(h_obs, ln_g, ln_b, Wv, bv,
                                                      W1, b1, W2, v, A4, CW8, derived);
  if (derived) {
    gano_main_kernel<true><<<B_ * NQ, 256, 0, stream>>>(
        pos_obs, pos_query, obs_mask, W1, b1, (const float4*)W2, b2, v,
        (const float4*)A4, (const float4*)CW8, outp);
  } else {
    gano_main_kernel<false><<<B_ * NQ, 256, 0, stream>>>(
        pos_obs, pos_query, obs_mask, W1, b1, (const float4*)W2, b2, v,
        (const float4*)A4, (const float4*)CW8, outp);
  }
}